// Round 3
// baseline (376.822 us; speedup 1.0000x reference)
//
#include <hip/hip_runtime.h>
#include <math.h>

#define BATCH 2
#define NPTS  16384
#define KNBR  16
#define EPSV  1e-5f

__device__ __forceinline__ float lrelu_(float x){ return fmaxf(x, 0.2f*x); }

// 16-element dot product: 4 float4 weight loads starting at row[cb4], against s_[0..15]
__device__ __forceinline__ float dot16(const float4* __restrict__ row, int cb4, const float* s_){
    float4 w0 = row[cb4+0];
    float4 w1 = row[cb4+1];
    float4 w2 = row[cb4+2];
    float4 w3 = row[cb4+3];
    float hs;
    hs = w0.x*s_[0];
    hs = fmaf(w0.y, s_[1], hs);  hs = fmaf(w0.z, s_[2], hs);  hs = fmaf(w0.w, s_[3], hs);
    hs = fmaf(w1.x, s_[4], hs);  hs = fmaf(w1.y, s_[5], hs);  hs = fmaf(w1.z, s_[6], hs);  hs = fmaf(w1.w, s_[7], hs);
    hs = fmaf(w2.x, s_[8], hs);  hs = fmaf(w2.y, s_[9], hs);  hs = fmaf(w2.z, s_[10], hs); hs = fmaf(w2.w, s_[11], hs);
    hs = fmaf(w3.x, s_[12], hs); hs = fmaf(w3.y, s_[13], hs); hs = fmaf(w3.z, s_[14], hs); hs = fmaf(w3.w, s_[15], hs);
    return hs;
}

// 16 output rows of a 64x64 matvec; input vector spread over the 4-lane quad as fA..fD
__device__ __forceinline__ void matvec_qtr(
    const float4* __restrict__ Wv_, const float* __restrict__ bias,
    int d0, int c0, int c1, int c2, int c3,
    const float* fA, const float* fB, const float* fC, const float* fD,
    float4* __restrict__ outp)
{
#pragma unroll
    for (int i4=0;i4<4;++i4){
        float accr[4];
#pragma unroll
        for (int r=0;r<4;++r){
            const int o = d0 + i4*4 + r;
            const float4* row = Wv_ + o*16;
            float hs = bias[o];
            hs += dot16(row, c0, fA);
            hs += dot16(row, c1, fB);
            hs += dot16(row, c2, fC);
            hs += dot16(row, c3, fD);
            accr[r] = hs;
        }
        outp[i4] = make_float4(accr[0], accr[1], accr[2], accr[3]);
    }
}

// Kernel 1: per point compute f = relu(bn1(W1@feat)), q = Wq f + bq, k, v.
// thread = (point, quarter): lane qq owns channels [16qq, 16qq+16)
__global__ __launch_bounds__(256) void qkvf_kernel(
    const float* __restrict__ feature,
    const float* __restrict__ W1, const float* __restrict__ bn1,
    const float* __restrict__ Wq, const float* __restrict__ bq,
    const float* __restrict__ Wk, const float* __restrict__ bk,
    const float* __restrict__ Wv, const float* __restrict__ bv,
    float* __restrict__ f_ws, float* __restrict__ q_ws,
    float* __restrict__ k_ws, float* __restrict__ v_ws)
{
    const int tid = blockIdx.x*256 + threadIdx.x;   // 0 .. B*N*4-1
    const int qq  = tid & 3;
    const int p   = tid >> 2;                        // 0 .. B*N-1
    const int b   = p >> 14;
    const int n   = p & (NPTS-1);
    const int d0  = qq*16;

    float feat[32];
    const float* fbase = feature + b*32*NPTS + n;
#pragma unroll
    for (int c=0;c<32;++c) feat[c] = fbase[c*NPTS];

    float fv[16];
    const float4* W1v = (const float4*)W1;
#pragma unroll
    for (int i=0;i<16;++i){
        const int d = d0+i;
        const float4* row = W1v + d*8;               // 32 floats per row
        float hs = dot16(row, 0, feat) + dot16(row, 4, feat+16);
        const float s = bn1[d]*rsqrtf(bn1[192+d]+EPSV);
        fv[i] = fmaxf(fmaf(hs, s, fmaf(-bn1[128+d], s, bn1[64+d])), 0.f);
    }
    {
        float4* fo = (float4*)(f_ws + p*64 + d0);
#pragma unroll
        for (int i4=0;i4<4;++i4) fo[i4] = make_float4(fv[4*i4],fv[4*i4+1],fv[4*i4+2],fv[4*i4+3]);
    }
    // exchange f across the quad: fB = lane^1's chunk, fC = lane^2's, fD = lane^3's
    float fB[16], fC[16], fD[16];
#pragma unroll
    for (int i=0;i<16;++i){
        fB[i] = __shfl_xor(fv[i], 1);
        fC[i] = __shfl_xor(fv[i], 2);
        fD[i] = __shfl_xor(fB[i], 2);
    }
    const int c0 = (qq^0)*4, c1 = (qq^1)*4, c2 = (qq^2)*4, c3 = (qq^3)*4;

    matvec_qtr((const float4*)Wq, bq, d0, c0,c1,c2,c3, fv,fB,fC,fD, (float4*)(q_ws + p*64 + d0));
    matvec_qtr((const float4*)Wk, bk, d0, c0,c1,c2,c3, fv,fB,fC,fD, (float4*)(k_ws + p*64 + d0));
    matvec_qtr((const float4*)Wv, bv, d0, c0,c1,c2,c3, fv,fB,fC,fD, (float4*)(v_ws + p*64 + d0));
}

// Kernel 2: neighbor gather + pos-MLP + attention weights + softmax + combine
//           + bn_mid + W2 + bn2 + residual + lrelu → output (B,64,N)
__global__ __launch_bounds__(256) void attn_kernel(
    const float* __restrict__ xyz, const int* __restrict__ nidx,
    const float* __restrict__ Wp1, const float* __restrict__ bnp1,
    const float* __restrict__ Wp2, const float* __restrict__ bp2,
    const float* __restrict__ bnw0,
    const float* __restrict__ Ww1, const float* __restrict__ bnw1,
    const float* __restrict__ Ww2, const float* __restrict__ bw2,
    const float* __restrict__ bn_mid,
    const float* __restrict__ W2, const float* __restrict__ bn2,
    const float* __restrict__ f_ws, const float* __restrict__ q_ws,
    const float* __restrict__ k_ws, const float* __restrict__ v_ws,
    float* __restrict__ out)
{
    const int tid = blockIdx.x*256 + threadIdx.x;   // 0 .. B*N*4-1
    const int qq  = tid & 3;
    const int p   = tid >> 2;
    const int b   = p >> 14;
    const int n   = p & (NPTS-1);
    const int d0  = qq*16;

    // pos-MLP stage-1 constants (shared, tiny)
    float wp1[9];
#pragma unroll
    for (int t=0;t<9;++t) wp1[t]=Wp1[t];
    float sp1[3], tp1[3];
#pragma unroll
    for (int o=0;o<3;++o){
        const float s = bnp1[o]*rsqrtf(bnp1[9+o]+EPSV);
        sp1[o]=s; tp1[o]=fmaf(-bnp1[6+o], s, bnp1[3+o]);
    }
    float sw1[8], tw1[8];
#pragma unroll
    for (int j=0;j<8;++j){
        const float s = bnw1[j]*rsqrtf(bnw1[24+j]+EPSV);
        sw1[j]=s; tw1[j]=fmaf(-bnw1[16+j], s, bnw1[8+j]);
    }
    // fold bnw0 and q into s0/qc:  wl = lrelu(s0*(xk+pr) + qc),  qc = t0 - s0*q
    float s0[16], qc[16];
    {
        const float4* qp4 = (const float4*)(q_ws + p*64 + d0);
        float qv[16];
#pragma unroll
        for (int i4=0;i4<4;++i4){ float4 t=qp4[i4]; qv[4*i4]=t.x; qv[4*i4+1]=t.y; qv[4*i4+2]=t.z; qv[4*i4+3]=t.w; }
#pragma unroll
        for (int i=0;i<16;++i){
            const int d = d0+i;
            const float s = bnw0[d]*rsqrtf(bnw0[192+d]+EPSV);
            s0[i]=s;
            qc[i]=fmaf(-bnw0[128+d], s, bnw0[64+d]) - s*qv[i];
        }
    }

    float m[8], l[8], acc[16];
#pragma unroll
    for (int j=0;j<8;++j){ m[j]=-3.0e38f; l[j]=0.f; }
#pragma unroll
    for (int i=0;i<16;++i) acc[i]=0.f;

    const int* nip = nidx + p*16;
    const float4* Ww1v = (const float4*)Ww1;
    const float4* Ww2v = (const float4*)Ww2;
    const float4* Wp2v = (const float4*)Wp2;
    const float4* bp2v = (const float4*)(bp2 + d0);
    const int cw = qq*4;

    for (int k=0;k<KNBR;++k){
        const int ni   = nip[k];
        const int rowb = (b<<14) + ni;               // b*N + idx
        // neighbor xyz → t3 = relu(bnp1(Wp1 @ xyz))
        const float* xp = xyz + rowb*3;
        const float x0=xp[0], x1=xp[1], x2v=xp[2];
        float t3[3];
#pragma unroll
        for (int o=0;o<3;++o){
            const float u = fmaf(wp1[3*o], x0, fmaf(wp1[3*o+1], x1, wp1[3*o+2]*x2v));
            t3[o] = fmaxf(fmaf(u, sp1[o], tp1[o]), 0.f);
        }
        // Wp2 / bp2 chunk for this lane's 16 channels (L1-hot reloads each k)
        float wp2f[48], bp2f[16];
#pragma unroll
        for (int t=0;t<12;++t){ float4 w = Wp2v[12*qq+t]; wp2f[4*t]=w.x; wp2f[4*t+1]=w.y; wp2f[4*t+2]=w.z; wp2f[4*t+3]=w.w; }
#pragma unroll
        for (int t=0;t<4;++t){  float4 w = bp2v[t];      bp2f[4*t]=w.x; bp2f[4*t+1]=w.y; bp2f[4*t+2]=w.z; bp2f[4*t+3]=w.w; }
        // gather k-row chunk, compute pr and wl
        const float4* kp = (const float4*)(k_ws + rowb*64 + d0);
        float pr[16], wl[16];
#pragma unroll
        for (int i4=0;i4<4;++i4){
            const float4 xk = kp[i4];
            const float xkv[4] = {xk.x, xk.y, xk.z, xk.w};
#pragma unroll
            for (int r=0;r<4;++r){
                const int i = 4*i4+r;
                const float prv = fmaf(wp2f[3*i], t3[0], fmaf(wp2f[3*i+1], t3[1], fmaf(wp2f[3*i+2], t3[2], bp2f[i])));
                pr[i] = prv;
                wl[i] = lrelu_(fmaf(s0[i], xkv[r]+prv, qc[i]));
            }
        }
        // y_j = Ww1[j,:] . wl over all 64 channels (quad butterfly reduce)
        float y[8];
#pragma unroll
        for (int j=0;j<8;++j){
            float yy = dot16(Ww1v + j*16, cw, wl);
            yy += __shfl_xor(yy, 1);
            yy += __shfl_xor(yy, 2);
            y[j] = yy;
        }
        // z = relu(bnw1(y));  w2 = Ww2 @ z + bw2
#pragma unroll
        for (int j=0;j<8;++j) y[j] = fmaxf(fmaf(y[j], sw1[j], tw1[j]), 0.f);
        float w2[8];
#pragma unroll
        for (int j=0;j<8;++j){
            const float4 wa = Ww2v[2*j], wb = Ww2v[2*j+1];
            float s = bw2[j];
            s = fmaf(wa.x, y[0], s); s = fmaf(wa.y, y[1], s); s = fmaf(wa.z, y[2], s); s = fmaf(wa.w, y[3], s);
            s = fmaf(wb.x, y[4], s); s = fmaf(wb.y, y[5], s); s = fmaf(wb.z, y[6], s); s = fmaf(wb.w, y[7], s);
            w2[j] = s;
        }
        // online softmax over k (per j)
        float sc[8], e[8];
#pragma unroll
        for (int j=0;j<8;++j){
            const float mn = fmaxf(m[j], w2[j]);
            sc[j] = __expf(m[j]-mn);
            e[j]  = __expf(w2[j]-mn);
            l[j]  = fmaf(l[j], sc[j], e[j]);
            m[j]  = mn;
        }
        // gather v-row chunk and accumulate (xv+pr) * e[d%8]
        const float4* vp = (const float4*)(v_ws + rowb*64 + d0);
#pragma unroll
        for (int i4=0;i4<4;++i4){
            const float4 xv = vp[i4];
            const float xvv[4] = {xv.x,xv.y,xv.z,xv.w};
#pragma unroll
            for (int r=0;r<4;++r){
                const int i = 4*i4+r;
                acc[i] = fmaf(acc[i], sc[i&7], (xvv[r]+pr[i])*e[i&7]);
            }
        }
    }
    // normalize, bn_mid + lrelu
    float linv[8];
#pragma unroll
    for (int j=0;j<8;++j) linv[j] = 1.f/l[j];
    float xm[16];
#pragma unroll
    for (int i=0;i<16;++i){
        const int d = d0+i;
        const float s = bn_mid[d]*rsqrtf(bn_mid[192+d]+EPSV);
        const float xx = acc[i]*linv[i&7];
        xm[i] = lrelu_(fmaf(xx, s, fmaf(-bn_mid[128+d], s, bn_mid[64+d])));
    }
    // exchange across quad for the full 64-vector
    float xB[16], xC[16], xD[16];
#pragma unroll
    for (int i=0;i<16;++i){
        xB[i]=__shfl_xor(xm[i], 1);
        xC[i]=__shfl_xor(xm[i], 2);
        xD[i]=__shfl_xor(xB[i], 2);
    }
    const int c0=(qq^0)*4, c1=(qq^1)*4, c2=(qq^2)*4, c3=(qq^3)*4;
    const float4* W2v = (const float4*)W2;
    const float* fp = f_ws + p*64 + d0;
    float* op = out + (b*64 + d0)*NPTS + n;
#pragma unroll
    for (int i=0;i<16;++i){
        const int o = d0+i;
        const float4* row = W2v + o*16;
        float hs = dot16(row,c0,xm) + dot16(row,c1,xB) + dot16(row,c2,xC) + dot16(row,c3,xD);
        const float s = bn2[o]*rsqrtf(bn2[192+o]+EPSV);
        const float x2r = fmaf(hs, s, fmaf(-bn2[128+o], s, bn2[64+o]));
        op[i*NPTS] = lrelu_(fp[i] + x2r);
    }
}

extern "C" void kernel_launch(void* const* d_in, const int* in_sizes, int n_in,
                              void* d_out, int out_size, void* d_ws, size_t ws_size,
                              hipStream_t stream) {
    const float* feature = (const float*)d_in[0];
    const float* xyz     = (const float*)d_in[1];
    const float* W1      = (const float*)d_in[2];
    const float* bn1     = (const float*)d_in[3];
    const float* Wq      = (const float*)d_in[4];
    const float* bq      = (const float*)d_in[5];
    const float* Wk      = (const float*)d_in[6];
    const float* bk      = (const float*)d_in[7];
    const float* Wv      = (const float*)d_in[8];
    const float* bv      = (const float*)d_in[9];
    const float* Wp1     = (const float*)d_in[10];
    const float* bnp1    = (const float*)d_in[11];
    const float* Wp2     = (const float*)d_in[12];
    const float* bp2     = (const float*)d_in[13];
    const float* bnw0    = (const float*)d_in[14];
    const float* Ww1     = (const float*)d_in[15];
    const float* bnw1    = (const float*)d_in[16];
    const float* Ww2     = (const float*)d_in[17];
    const float* bw2     = (const float*)d_in[18];
    const float* bn_mid  = (const float*)d_in[19];
    const float* W2      = (const float*)d_in[20];
    const float* bn2     = (const float*)d_in[21];
    const int*   nidx    = (const int*)d_in[22];
    float* out = (float*)d_out;

    // workspace: 4 arrays of B*N*64 floats = 4 * 8MB = 32MB
    float* ws   = (float*)d_ws;
    float* f_ws = ws;
    float* q_ws = ws + 2097152;
    float* k_ws = ws + 2*2097152;
    float* v_ws = ws + 3*2097152;

    // B*N*4 threads each
    qkvf_kernel<<<512, 256, 0, stream>>>(feature, W1, bn1, Wq, bq, Wk, bk, Wv, bv,
                                         f_ws, q_ws, k_ws, v_ws);
    attn_kernel<<<512, 256, 0, stream>>>(xyz, nidx, Wp1, bnp1, Wp2, bp2, bnw0,
                                         Ww1, bnw1, Ww2, bw2, bn_mid, W2, bn2,
                                         f_ws, q_ws, k_ws, v_ws, out);
}

// Round 4
// 271.009 us; speedup vs baseline: 1.3904x; 1.3904x over previous
//
#include <hip/hip_runtime.h>
#include <math.h>

#define NPTS 16384
#define KNBR 16
#define EPSV 1e-5f

__device__ __forceinline__ float lrelu_(float x){ return fmaxf(x, 0.2f*x); }

__device__ __forceinline__ float dot16(const float4* __restrict__ row, int cb4, const float* s_){
    float4 w0 = row[cb4+0];
    float4 w1 = row[cb4+1];
    float4 w2 = row[cb4+2];
    float4 w3 = row[cb4+3];
    float hs;
    hs = w0.x*s_[0];
    hs = fmaf(w0.y, s_[1], hs);  hs = fmaf(w0.z, s_[2], hs);  hs = fmaf(w0.w, s_[3], hs);
    hs = fmaf(w1.x, s_[4], hs);  hs = fmaf(w1.y, s_[5], hs);  hs = fmaf(w1.z, s_[6], hs);  hs = fmaf(w1.w, s_[7], hs);
    hs = fmaf(w2.x, s_[8], hs);  hs = fmaf(w2.y, s_[9], hs);  hs = fmaf(w2.z, s_[10], hs); hs = fmaf(w2.w, s_[11], hs);
    hs = fmaf(w3.x, s_[12], hs); hs = fmaf(w3.y, s_[13], hs); hs = fmaf(w3.z, s_[14], hs); hs = fmaf(w3.w, s_[15], hs);
    return hs;
}

// ---------------- Kernel 1: f/q/k/v (8 lanes/point, LDS weights, conflict-free) ----------------
__global__ __launch_bounds__(256) void qkvf_kernel(
    const float* __restrict__ feature,
    const float* __restrict__ W1, const float* __restrict__ bn1,
    const float* __restrict__ Wq, const float* __restrict__ bq,
    const float* __restrict__ Wk, const float* __restrict__ bk,
    const float* __restrict__ Wv, const float* __restrict__ bv,
    float* __restrict__ f_ws, float* __restrict__ q_ws,
    float* __restrict__ k_ws, float* __restrict__ v_ws)
{
    __shared__ float lw1[64*36];
    __shared__ float lwq[64*68];
    __shared__ float lwk[64*68];
    __shared__ float lwv[64*68];
    __shared__ float lbq[64], lbk[64], lbv[64], ls1[64], lt1[64];

    const int t = threadIdx.x;
#pragma unroll
    for (int r=0;r<8;++r){
        const int idx = t + r*256;                  // 0..2047
        lw1[(idx>>5)*36 + (idx&31)] = W1[idx];
    }
#pragma unroll
    for (int r=0;r<16;++r){
        const int idx = t + r*256;                  // 0..4095
        const int o = idx>>6, c = idx&63;
        lwq[o*68+c] = Wq[idx];
        lwk[o*68+c] = Wk[idx];
        lwv[o*68+c] = Wv[idx];
    }
    if (t < 64){
        lbq[t]=bq[t]; lbk[t]=bk[t]; lbv[t]=bv[t];
        const float s = bn1[t]*rsqrtf(bn1[192+t]+EPSV);
        ls1[t]=s; lt1[t]=fmaf(-bn1[128+t], s, bn1[64+t]);
    }
    __syncthreads();

    const int tid   = blockIdx.x*256 + t;           // 0 .. B*N*8-1
    const int ll    = tid & 7;
    const int p     = tid >> 3;                     // 0 .. B*N-1
    const int b     = p >> 14;
    const int n     = p & (NPTS-1);
    const int obase = (t & 63) & 56;

    float ft[4];
    const float* fbase = feature + b*32*NPTS + n;
#pragma unroll
    for (int u=0;u<4;++u) ft[u] = fbase[(8*u+ll)*NPTS];

    float Yf0[4],Yf1[4],Yf2[4],Yf3[4],Yf4[4],Yf5[4],Yf6[4],Yf7[4];
#pragma unroll
    for (int u=0;u<4;++u){
        Yf0[u]=__shfl(ft[u], obase+0); Yf1[u]=__shfl(ft[u], obase+1);
        Yf2[u]=__shfl(ft[u], obase+2); Yf3[u]=__shfl(ft[u], obase+3);
        Yf4[u]=__shfl(ft[u], obase+4); Yf5[u]=__shfl(ft[u], obase+5);
        Yf6[u]=__shfl(ft[u], obase+6); Yf7[u]=__shfl(ft[u], obase+7);
    }

    float fv[8];
#pragma unroll
    for (int i=0;i<8;++i){
        const int o = 8*i + ll;
        const float4* row = (const float4*)(lw1 + o*36);
        float hs = 0.f;
#pragma unroll
        for (int u=0;u<4;++u){
            const float4 wa = row[2*u], wb = row[2*u+1];
            hs = fmaf(wa.x,Yf0[u],hs); hs = fmaf(wa.y,Yf1[u],hs);
            hs = fmaf(wa.z,Yf2[u],hs); hs = fmaf(wa.w,Yf3[u],hs);
            hs = fmaf(wb.x,Yf4[u],hs); hs = fmaf(wb.y,Yf5[u],hs);
            hs = fmaf(wb.z,Yf6[u],hs); hs = fmaf(wb.w,Yf7[u],hs);
        }
        fv[i] = fmaxf(fmaf(hs, ls1[o], lt1[o]), 0.f);
        f_ws[p*64+o] = fv[i];
    }

    float Y0[8],Y1[8],Y2[8],Y3[8],Y4[8],Y5[8],Y6[8],Y7[8];
#pragma unroll
    for (int i=0;i<8;++i){
        Y0[i]=__shfl(fv[i], obase+0); Y1[i]=__shfl(fv[i], obase+1);
        Y2[i]=__shfl(fv[i], obase+2); Y3[i]=__shfl(fv[i], obase+3);
        Y4[i]=__shfl(fv[i], obase+4); Y5[i]=__shfl(fv[i], obase+5);
        Y6[i]=__shfl(fv[i], obase+6); Y7[i]=__shfl(fv[i], obase+7);
    }

#define QKV_MATVEC(LW, LB, OUTP)                                      \
    _Pragma("unroll")                                                 \
    for (int i=0;i<8;++i){                                            \
        const int o = 8*i+ll;                                         \
        const float4* row = (const float4*)(LW + o*68);               \
        float hs = LB[o];                                             \
        _Pragma("unroll")                                             \
        for (int u=0;u<8;++u){                                        \
            const float4 wa = row[2*u], wb = row[2*u+1];              \
            hs = fmaf(wa.x,Y0[u],hs); hs = fmaf(wa.y,Y1[u],hs);       \
            hs = fmaf(wa.z,Y2[u],hs); hs = fmaf(wa.w,Y3[u],hs);       \
            hs = fmaf(wb.x,Y4[u],hs); hs = fmaf(wb.y,Y5[u],hs);       \
            hs = fmaf(wb.z,Y6[u],hs); hs = fmaf(wb.w,Y7[u],hs);       \
        }                                                             \
        OUTP[p*64+o] = hs;                                            \
    }

    QKV_MATVEC(lwq, lbq, q_ws)
    QKV_MATVEC(lwk, lbk, k_ws)
    QKV_MATVEC(lwv, lbv, v_ws)
#undef QKV_MATVEC
}

// ---------------- Kernel 2: gather + attention + epilogue ----------------
__global__ __launch_bounds__(256) void attn_kernel(
    const float* __restrict__ xyz, const int* __restrict__ nidx,
    const float* __restrict__ Wp1, const float* __restrict__ bnp1,
    const float* __restrict__ Wp2, const float* __restrict__ bp2,
    const float* __restrict__ bnw0,
    const float* __restrict__ Ww1, const float* __restrict__ bnw1,
    const float* __restrict__ Ww2, const float* __restrict__ bw2,
    const float* __restrict__ bn_mid,
    const float* __restrict__ W2, const float* __restrict__ bn2,
    const float* __restrict__ f_ws, const float* __restrict__ q_ws,
    const float* __restrict__ k_ws, const float* __restrict__ v_ws,
    float* __restrict__ out)
{
    __shared__ float lww1[8*64];
    __shared__ float lw2[64*68];
    __shared__ float ls2[64], lt2[64], lsm[64], ltm[64];

    const int t = threadIdx.x;
#pragma unroll
    for (int r=0;r<2;++r){ const int idx=t+r*256; lww1[idx]=Ww1[idx]; }
#pragma unroll
    for (int r=0;r<16;++r){
        const int idx=t+r*256; const int o=idx>>6, c=idx&63;
        lw2[o*68+c]=W2[idx];
    }
    if (t<64){
        float s = bn2[t]*rsqrtf(bn2[192+t]+EPSV);
        ls2[t]=s; lt2[t]=fmaf(-bn2[128+t], s, bn2[64+t]);
        s = bn_mid[t]*rsqrtf(bn_mid[192+t]+EPSV);
        lsm[t]=s; ltm[t]=fmaf(-bn_mid[128+t], s, bn_mid[64+t]);
    }
    __syncthreads();

    const int tid   = blockIdx.x*256 + t;
    const int qq    = tid & 3;
    const int p     = tid >> 2;
    const int b     = p >> 14;
    const int n     = p & (NPTS-1);
    const int d0    = qq*16;
    const int qbase = (t & 63) & 60;

    float wp1[9];
#pragma unroll
    for (int u=0;u<9;++u) wp1[u]=Wp1[u];
    float sp1[3], tp1[3];
#pragma unroll
    for (int o=0;o<3;++o){
        const float s = bnp1[o]*rsqrtf(bnp1[9+o]+EPSV);
        sp1[o]=s; tp1[o]=fmaf(-bnp1[6+o], s, bnp1[3+o]);
    }
    float sw1[8], tw1[8];
#pragma unroll
    for (int j=0;j<8;++j){
        const float s = bnw1[j]*rsqrtf(bnw1[24+j]+EPSV);
        sw1[j]=s; tw1[j]=fmaf(-bnw1[16+j], s, bnw1[8+j]);
    }
    float wp2f[48];
#pragma unroll
    for (int u=0;u<12;++u){
        const float4 w = ((const float4*)Wp2)[12*qq+u];
        wp2f[4*u]=w.x; wp2f[4*u+1]=w.y; wp2f[4*u+2]=w.z; wp2f[4*u+3]=w.w;
    }
    float ww2r[16]; float bw2r0, bw2r1;
    {
        const float4* wv = (const float4*)Ww2;
        const float4 a0=wv[4*qq], a1=wv[4*qq+1], b0=wv[4*qq+2], b1=wv[4*qq+3];
        ww2r[0]=a0.x; ww2r[1]=a0.y; ww2r[2]=a0.z; ww2r[3]=a0.w;
        ww2r[4]=a1.x; ww2r[5]=a1.y; ww2r[6]=a1.z; ww2r[7]=a1.w;
        ww2r[8]=b0.x; ww2r[9]=b0.y; ww2r[10]=b0.z; ww2r[11]=b0.w;
        ww2r[12]=b1.x; ww2r[13]=b1.y; ww2r[14]=b1.z; ww2r[15]=b1.w;
        bw2r0 = bw2[2*qq]; bw2r1 = bw2[2*qq+1];
    }
    float s0[16], qc[16];
    {
        const float4* qp4  = (const float4*)(q_ws + p*64 + d0);
        const float4* bp2v = (const float4*)(bp2 + d0);
        float qv[16], bpv[16];
#pragma unroll
        for (int i4=0;i4<4;++i4){
            const float4 tq=qp4[i4];  qv[4*i4]=tq.x; qv[4*i4+1]=tq.y; qv[4*i4+2]=tq.z; qv[4*i4+3]=tq.w;
            const float4 tb=bp2v[i4]; bpv[4*i4]=tb.x; bpv[4*i4+1]=tb.y; bpv[4*i4+2]=tb.z; bpv[4*i4+3]=tb.w;
        }
#pragma unroll
        for (int i=0;i<16;++i){
            const int d = d0+i;
            const float s = bnw0[d]*rsqrtf(bnw0[192+d]+EPSV);
            s0[i]=s;
            qc[i]=fmaf(-bnw0[128+d], s, bnw0[64+d]) + s*(bpv[i]-qv[i]);
        }
    }

    float m[8], l[8], acc[16];
#pragma unroll
    for (int j=0;j<8;++j){ m[j]=-3.0e38f; l[j]=0.f; }
#pragma unroll
    for (int i=0;i<16;++i) acc[i]=0.f;

    const int* nip = nidx + p*16;

#pragma unroll 2
    for (int k=0;k<KNBR;++k){
        const int ni   = nip[k];
        const int rowb = (b<<14) + ni;
        const float4* kp = (const float4*)(k_ws + rowb*64 + d0);
        const float4 xk0=kp[0], xk1=kp[1], xk2=kp[2], xk3=kp[3];
        const float* xp = xyz + rowb*3;
        const float x0=xp[0], x1=xp[1], x2v=xp[2];

        float t3[3];
#pragma unroll
        for (int o=0;o<3;++o){
            const float u = fmaf(wp1[3*o], x0, fmaf(wp1[3*o+1], x1, wp1[3*o+2]*x2v));
            t3[o] = fmaxf(fmaf(u, sp1[o], tp1[o]), 0.f);
        }

        float wl[16];
        {
            const float xkv0[4]={xk0.x,xk0.y,xk0.z,xk0.w};
            const float xkv1[4]={xk1.x,xk1.y,xk1.z,xk1.w};
            const float xkv2[4]={xk2.x,xk2.y,xk2.z,xk2.w};
            const float xkv3[4]={xk3.x,xk3.y,xk3.z,xk3.w};
#pragma unroll
            for (int r=0;r<4;++r){
                const float prv0 = fmaf(wp2f[3*r],      t3[0], fmaf(wp2f[3*r+1],    t3[1], wp2f[3*r+2]*t3[2]));
                const float prv1 = fmaf(wp2f[12+3*r],   t3[0], fmaf(wp2f[13+3*r],   t3[1], wp2f[14+3*r]*t3[2]));
                const float prv2 = fmaf(wp2f[24+3*r],   t3[0], fmaf(wp2f[25+3*r],   t3[1], wp2f[26+3*r]*t3[2]));
                const float prv3 = fmaf(wp2f[36+3*r],   t3[0], fmaf(wp2f[37+3*r],   t3[1], wp2f[38+3*r]*t3[2]));
                wl[r]    = lrelu_(fmaf(s0[r],    xkv0[r]+prv0, qc[r]));
                wl[4+r]  = lrelu_(fmaf(s0[4+r],  xkv1[r]+prv1, qc[4+r]));
                wl[8+r]  = lrelu_(fmaf(s0[8+r],  xkv2[r]+prv2, qc[8+r]));
                wl[12+r] = lrelu_(fmaf(s0[12+r], xkv3[r]+prv3, qc[12+r]));
            }
        }

        float y[8];
#pragma unroll
        for (int j=0;j<8;++j){
            const float4* wr = (const float4*)(lww1 + j*64 + d0);
            float yy = dot16(wr, 0, wl);
            yy += __shfl_xor(yy, 1);
            yy += __shfl_xor(yy, 2);
            y[j] = yy;
        }
#pragma unroll
        for (int j=0;j<8;++j) y[j] = fmaxf(fmaf(y[j], sw1[j], tw1[j]), 0.f);
        float w2p0 = bw2r0, w2p1 = bw2r1;
#pragma unroll
        for (int j=0;j<8;++j){
            w2p0 = fmaf(ww2r[j],   y[j], w2p0);
            w2p1 = fmaf(ww2r[8+j], y[j], w2p1);
        }
        float w2[8];
        w2[0]=__shfl(w2p0, qbase+0); w2[1]=__shfl(w2p1, qbase+0);
        w2[2]=__shfl(w2p0, qbase+1); w2[3]=__shfl(w2p1, qbase+1);
        w2[4]=__shfl(w2p0, qbase+2); w2[5]=__shfl(w2p1, qbase+2);
        w2[6]=__shfl(w2p0, qbase+3); w2[7]=__shfl(w2p1, qbase+3);

        float sc[8], e[8];
#pragma unroll
        for (int j=0;j<8;++j){
            const float mn = fmaxf(m[j], w2[j]);
            sc[j] = __expf(m[j]-mn);
            e[j]  = __expf(w2[j]-mn);
            l[j]  = fmaf(l[j], sc[j], e[j]);
            m[j]  = mn;
        }

        const float4* vp = (const float4*)(v_ws + rowb*64 + d0);
        const float4 xv0=vp[0], xv1=vp[1], xv2=vp[2], xv3=vp[3];
        {
            const float xvv0[4]={xv0.x,xv0.y,xv0.z,xv0.w};
            const float xvv1[4]={xv1.x,xv1.y,xv1.z,xv1.w};
            const float xvv2[4]={xv2.x,xv2.y,xv2.z,xv2.w};
            const float xvv3[4]={xv3.x,xv3.y,xv3.z,xv3.w};
#pragma unroll
            for (int r=0;r<4;++r){
                const float prv0 = fmaf(wp2f[3*r],      t3[0], fmaf(wp2f[3*r+1],    t3[1], wp2f[3*r+2]*t3[2]));
                const float prv1 = fmaf(wp2f[12+3*r],   t3[0], fmaf(wp2f[13+3*r],   t3[1], wp2f[14+3*r]*t3[2]));
                const float prv2 = fmaf(wp2f[24+3*r],   t3[0], fmaf(wp2f[25+3*r],   t3[1], wp2f[26+3*r]*t3[2]));
                const float prv3 = fmaf(wp2f[36+3*r],   t3[0], fmaf(wp2f[37+3*r],   t3[1], wp2f[38+3*r]*t3[2]));
                acc[r]    = fmaf(acc[r],    sc[r],   (xvv0[r]+prv0)*e[r]);
                acc[4+r]  = fmaf(acc[4+r],  sc[4+r], (xvv1[r]+prv1)*e[4+r]);
                acc[8+r]  = fmaf(acc[8+r],  sc[r],   (xvv2[r]+prv2)*e[r]);
                acc[12+r] = fmaf(acc[12+r], sc[4+r], (xvv3[r]+prv3)*e[4+r]);
            }
        }
    }

    float linv[8];
#pragma unroll
    for (int j=0;j<8;++j) linv[j] = 1.f/l[j];
    float xm[16];
    {
        const float4* bp2v = (const float4*)(bp2 + d0);
#pragma unroll
        for (int i4=0;i4<4;++i4){
            const float4 tb = bp2v[i4];
            const float bpv[4]={tb.x,tb.y,tb.z,tb.w};
#pragma unroll
            for (int r=0;r<4;++r){
                const int i = 4*i4+r;
                const int d = d0+i;
                const float xx = fmaf(acc[i], linv[i&7], bpv[r]);
                xm[i] = lrelu_(fmaf(xx, lsm[d], ltm[d]));
            }
        }
    }
    float Yx0[16],Yx1[16],Yx2[16],Yx3[16];
#pragma unroll
    for (int i=0;i<16;++i){
        Yx0[i]=__shfl(xm[i], qbase+0);
        Yx1[i]=__shfl(xm[i], qbase+1);
        Yx2[i]=__shfl(xm[i], qbase+2);
        Yx3[i]=__shfl(xm[i], qbase+3);
    }
    const float* fpw = f_ws + p*64;
#pragma unroll
    for (int i=0;i<16;++i){
        const int o = 4*i+qq;
        const float4* row = (const float4*)(lw2 + o*68);
        float hs = dot16(row,0,Yx0) + dot16(row,4,Yx1) + dot16(row,8,Yx2) + dot16(row,12,Yx3);
        const float x2r = fmaf(hs, ls2[o], lt2[o]);
        out[(b*64+o)*NPTS + n] = lrelu_(fpw[o] + x2r);
    }
}

extern "C" void kernel_launch(void* const* d_in, const int* in_sizes, int n_in,
                              void* d_out, int out_size, void* d_ws, size_t ws_size,
                              hipStream_t stream) {
    const float* feature = (const float*)d_in[0];
    const float* xyz     = (const float*)d_in[1];
    const float* W1      = (const float*)d_in[2];
    const float* bn1     = (const float*)d_in[3];
    const float* Wq      = (const float*)d_in[4];
    const float* bq      = (const float*)d_in[5];
    const float* Wk      = (const float*)d_in[6];
    const float* bk      = (const float*)d_in[7];
    const float* Wv      = (const float*)d_in[8];
    const float* bv      = (const float*)d_in[9];
    const float* Wp1     = (const float*)d_in[10];
    const float* bnp1    = (const float*)d_in[11];
    const float* Wp2     = (const float*)d_in[12];
    const float* bp2     = (const float*)d_in[13];
    const float* bnw0    = (const float*)d_in[14];
    const float* Ww1     = (const float*)d_in[15];
    const float* bnw1    = (const float*)d_in[16];
    const float* Ww2     = (const float*)d_in[17];
    const float* bw2     = (const float*)d_in[18];
    const float* bn_mid  = (const float*)d_in[19];
    const float* W2      = (const float*)d_in[20];
    const float* bn2     = (const float*)d_in[21];
    const int*   nidx    = (const int*)d_in[22];
    float* out = (float*)d_out;

    float* ws   = (float*)d_ws;
    float* f_ws = ws;
    float* q_ws = ws + 2097152;
    float* k_ws = ws + 2*2097152;
    float* v_ws = ws + 3*2097152;

    qkvf_kernel<<<1024, 256, 0, stream>>>(feature, W1, bn1, Wq, bq, Wk, bk, Wv, bv,
                                          f_ws, q_ws, k_ws, v_ws);
    attn_kernel<<<512, 256, 0, stream>>>(xyz, nidx, Wp1, bnp1, Wp2, bp2, bnw0,
                                         Ww1, bnw1, Ww2, bw2, bn_mid, W2, bn2,
                                         f_ws, q_ws, k_ws, v_ws, out);
}